// Round 5
// baseline (98.568 us; speedup 1.0000x reference)
//
#include <hip/hip_runtime.h>
#include <hip/hip_bf16.h>
#include <stdint.h>

typedef __attribute__((ext_vector_type(8))) short short8;
typedef __attribute__((ext_vector_type(4))) float f32x4;
typedef __attribute__((ext_vector_type(4))) unsigned short u16x4;

__device__ __forceinline__ float bf2f(unsigned short u) {
  union { unsigned int u; float f; } x; x.u = ((unsigned int)u) << 16; return x.f;
}
__device__ __forceinline__ unsigned short f2bf(float f) {
  union { float f; unsigned int u; } x; x.f = f;
  unsigned int u = x.u;
  return (unsigned short)((u + 0x7fffu + ((u >> 16) & 1u)) >> 16);
}

__device__ __forceinline__ void gload_lds16(const void* g, void* l) {
  __builtin_amdgcn_global_load_lds(
      (const __attribute__((address_space(1))) void*)g,
      (__attribute__((address_space(3))) void*)l, 16, 0, 0);
}

// ---------------- fp32 -> bf16 converts ----------------
__global__ void cvt4(const float* __restrict__ s, unsigned short* __restrict__ d) {
  int i = (blockIdx.x * 256 + threadIdx.x) * 4;
  f32x4 f = *(const f32x4*)(s + i);
  u16x4 o = { f2bf(f[0]), f2bf(f[1]), f2bf(f[2]), f2bf(f[3]) };
  *(u16x4*)(d + i) = o;
}

__global__ void cvt_w(const float* __restrict__ w0, const float* __restrict__ w1,
                      const float* __restrict__ w2, const float* __restrict__ w3,
                      unsigned short* __restrict__ dst) {
  const float* s = blockIdx.z == 0 ? w0 : blockIdx.z == 1 ? w1 : blockIdx.z == 2 ? w2 : w3;
  unsigned short* d = dst + (size_t)blockIdx.z * 1048576;
  int i = (blockIdx.x * 256 + threadIdx.x) * 4;
  f32x4 f = *(const f32x4*)(s + i);
  u16x4 o = { f2bf(f[0]), f2bf(f[1]), f2bf(f[2]), f2bf(f[3]) };
  *(u16x4*)(d + i) = o;
}

// ---------------- NT bf16 GEMM, 128xBN tile, BK=32, triple-buffer ring ----
// Counted-vmcnt pipeline: stage tile t+2 during compute of tile t.
// LDS chunk swizzle (both sides): source chunk and ds_read chunk XOR (row>>1)&3.
// SWAP=true: acc = mfma(Wfrag, Afrag) -> reg-dim walks the FEATURE dim ->
//            packed epilogue stores (u16x4 / f32x4).
// MODE 0 SWAP=1: z=blockIdx.z in {0,1} -> Q,K head-major [z][b][h][s][d]
// MODE 0 SWAP=0: V -> transposed [b][h][d][s] (reg-dim walks s)
// MODE 1 SWAP=1: O-proj -> fp32 row-major d_out
template <int MODE, bool SWAP, int BN>
__global__ __launch_bounds__(256)
void gemm_bt(const unsigned short* __restrict__ A,
             const unsigned short* __restrict__ Wbase,
             const float* __restrict__ bias0, const float* __restrict__ bias1,
             unsigned short* __restrict__ obf, float* __restrict__ of32) {
  const int K = 1024, NT = 32;
  constexpr int GX = 1024 / BN;   // blocks along N
  constexpr int LB = BN / 64;     // B-loads per thread per tile
  constexpr int NWC = BN / 64;    // wave cols
  constexpr int NWR = 4 / NWC;    // wave rows
  constexpr int MS = 128 / NWR;   // per-wave M span
  constexpr int MR = MS / 16;     // M repeats
  constexpr int ASZ = 128 * 32, BSZ = BN * 32;

  const int z = (MODE == 0 && SWAP) ? blockIdx.z : 2;
  const unsigned short* W =
      (MODE == 0 && SWAP) ? Wbase + ((size_t)blockIdx.z << 20) : Wbase;
  const float* bias = (MODE == 0 && SWAP && blockIdx.z == 1) ? bias1 : bias0;

  // XCD-aware bijective swizzle: nwg = GX*32, divisible by 8.
  constexpr int NWG = GX * 32;
  int flat = blockIdx.y * GX + blockIdx.x;
  int swz = (flat & 7) * (NWG / 8) + (flat >> 3);
  const int n0 = (swz % GX) * BN, m0 = (swz / GX) * 128;

  const int tid = threadIdx.x, lane = tid & 63, w = tid >> 6;
  const int wr = w / NWC, wc = w % NWC;
  const int fr = lane & 15, g = lane >> 4;

  __shared__ unsigned short lds[3][ASZ + BSZ];

  f32x4 acc[MR][4] = {};

#define STAGE(bi, t)                                                            \
  do {                                                                          \
    _Pragma("unroll") for (int i = 0; i < 2; ++i) {                             \
      int s = i * 256 + tid;                                                    \
      int row = s >> 2;                                                         \
      int gc = (s & 3) ^ ((row >> 1) & 3);                                      \
      gload_lds16(A + (size_t)(m0 + row) * K + (t) * 32 + gc * 8,               \
                  &lds[bi][s * 8]);                                             \
    }                                                                           \
    _Pragma("unroll") for (int i = 0; i < LB; ++i) {                            \
      int s = i * 256 + tid;                                                    \
      int row = s >> 2;                                                         \
      int gc = (s & 3) ^ ((row >> 1) & 3);                                      \
      gload_lds16(W + (size_t)(n0 + row) * K + (t) * 32 + gc * 8,               \
                  &lds[bi][ASZ + s * 8]);                                       \
    }                                                                           \
  } while (0)

#define COMPUTE(bi)                                                             \
  do {                                                                          \
    short8 af[MR], bfr[4];                                                      \
    _Pragma("unroll") for (int m = 0; m < MR; ++m) {                            \
      int ra = wr * MS + m * 16 + fr;                                           \
      af[m] = *(const short8*)&lds[bi][ra * 32 + ((g ^ ((ra >> 1) & 3)) * 8)];  \
    }                                                                           \
    _Pragma("unroll") for (int n = 0; n < 4; ++n) {                             \
      int rb2 = wc * 64 + n * 16 + fr;                                          \
      bfr[n] = *(const short8*)&lds[bi][ASZ + rb2 * 32 +                        \
                                        ((g ^ ((rb2 >> 1) & 3)) * 8)];          \
    }                                                                           \
    _Pragma("unroll") for (int m = 0; m < MR; ++m)                              \
        _Pragma("unroll") for (int n = 0; n < 4; ++n) {                         \
      if constexpr (SWAP)                                                       \
        acc[m][n] = __builtin_amdgcn_mfma_f32_16x16x32_bf16(bfr[n], af[m],      \
                                                            acc[m][n], 0, 0, 0);\
      else                                                                      \
        acc[m][n] = __builtin_amdgcn_mfma_f32_16x16x32_bf16(af[m], bfr[n],      \
                                                            acc[m][n], 0, 0, 0);\
    }                                                                           \
  } while (0)

  STAGE(0, 0);
  STAGE(1, 1);
  for (int t = 0; t < NT; ++t) {
    if (t < NT - 1) {
      if constexpr (BN == 128)
        asm volatile("s_waitcnt vmcnt(4)" ::: "memory");
      else
        asm volatile("s_waitcnt vmcnt(3)" ::: "memory");
    } else {
      asm volatile("s_waitcnt vmcnt(0)" ::: "memory");
    }
    __builtin_amdgcn_s_barrier();
    __builtin_amdgcn_sched_barrier(0);
    if (t + 2 < NT) STAGE((t + 2) % 3, t + 2);
    __builtin_amdgcn_s_setprio(1);
    COMPUTE(t % 3);
    __builtin_amdgcn_s_setprio(0);
  }
#undef STAGE
#undef COMPUTE

  if constexpr (SWAP) {
    // reg-dim i walks the feature/col dim (4 consecutive cols at g*4)
#pragma unroll
    for (int m = 0; m < MR; ++m) {
#pragma unroll
      for (int n = 0; n < 4; ++n) {
        int token = m0 + wr * MS + m * 16 + fr;
        int col0 = n0 + wc * 64 + n * 16 + g * 4;
        f32x4 bv = *(const f32x4*)&bias[col0];
        if (MODE == 0) {
          u16x4 pk;
#pragma unroll
          for (int i = 0; i < 4; ++i) pk[i] = f2bf(acc[m][n][i] + bv[i]);
          int hh = col0 >> 6, d0 = col0 & 63;
          int bb = token >> 11, s0 = token & 2047;
          *(u16x4*)&obf[(((size_t)(z * 32 + bb * 16 + hh)) * 2048 + s0) * 64 + d0] = pk;
        } else {
          f32x4 o;
#pragma unroll
          for (int i = 0; i < 4; ++i) o[i] = acc[m][n][i] + bv[i];
          *(f32x4*)&of32[(size_t)token * 1024 + col0] = o;
        }
      }
    }
  } else {
    // V: reg-dim i walks the token dim -> pack along s for [d][s] layout
#pragma unroll
    for (int m = 0; m < MR; ++m) {
#pragma unroll
      for (int n = 0; n < 4; ++n) {
        int col = n0 + wc * 64 + n * 16 + fr;
        float bias_v = bias[col];
        int row0 = m0 + wr * MS + m * 16 + g * 4;
        int hh = col >> 6, d = col & 63;
        int bb = row0 >> 11, s0 = row0 & 2047;
        u16x4 pk;
#pragma unroll
        for (int i = 0; i < 4; ++i) pk[i] = f2bf(acc[m][n][i] + bias_v);
        *(u16x4*)&obf[(((size_t)(64 + bb * 16 + hh)) * 64 + d) * 2048 + s0] = pk;
      }
    }
  }
}

// ---------------- MFMA flash attention, window=256 ----------------
__global__ __launch_bounds__(256)
void attn_mfma(const unsigned short* __restrict__ QKV, unsigned short* __restrict__ AO) {
  const int S = 2048;
  const int b = blockIdx.z, h = blockIdx.y;
  const int q0 = blockIdx.x * 128;
  const size_t hb = (size_t)(b * 16 + h);
  const unsigned short* Qh = QKV + hb * (S * 64);
  const unsigned short* Kh = QKV + 4194304 + hb * (S * 64);
  const unsigned short* Vt = QKV + 8388608 + hb * (S * 64);  // [64][2048]

  const int tid = threadIdx.x;
  const int lane = tid & 63, w = tid >> 6;
  const int c = lane & 15, g = lane >> 4;
  const int qw0 = q0 + 32 * w;

  __shared__ unsigned short Plds[4][1024];
  char* Pb = (char*)&Plds[w][0];

  short8 qa[2][2];
#pragma unroll
  for (int mi = 0; mi < 2; ++mi)
#pragma unroll
    for (int cs = 0; cs < 2; ++cs)
      qa[mi][cs] = *(const short8*)(Qh + (size_t)(qw0 + 16 * mi + c) * 64 + 32 * cs + g * 8);

  f32x4 o[2][4] = {};
  float mrow[2][4], lsum[2][4];
#pragma unroll
  for (int mi = 0; mi < 2; ++mi)
#pragma unroll
    for (int r = 0; r < 4; ++r) { mrow[mi][r] = -1e30f; lsum[mi][r] = 0.f; }

  int kt0 = qw0 - 256; if (kt0 < 0) kt0 = 0;
  const int ktlast = qw0;

  short8 kf[2][2], vf[4];
#pragma unroll
  for (int ni = 0; ni < 2; ++ni)
#pragma unroll
    for (int cs = 0; cs < 2; ++cs)
      kf[ni][cs] = *(const short8*)(Kh + (size_t)(kt0 + 16 * ni + c) * 64 + 32 * cs + g * 8);
#pragma unroll
  for (int ni = 0; ni < 4; ++ni)
    vf[ni] = *(const short8*)(Vt + (size_t)(16 * ni + c) * 2048 + kt0 + g * 8);

  for (int kt = kt0; kt <= ktlast; kt += 32) {
    const int ktn = (kt + 32 <= ktlast) ? kt + 32 : kt;
    short8 kfn[2][2], vfn[4];
#pragma unroll
    for (int ni = 0; ni < 2; ++ni)
#pragma unroll
      for (int cs = 0; cs < 2; ++cs)
        kfn[ni][cs] = *(const short8*)(Kh + (size_t)(ktn + 16 * ni + c) * 64 + 32 * cs + g * 8);
#pragma unroll
    for (int ni = 0; ni < 4; ++ni)
      vfn[ni] = *(const short8*)(Vt + (size_t)(16 * ni + c) * 2048 + ktn + g * 8);

    f32x4 sA[2][2] = {};
#pragma unroll
    for (int mi = 0; mi < 2; ++mi)
#pragma unroll
      for (int ni = 0; ni < 2; ++ni)
#pragma unroll
        for (int cs = 0; cs < 2; ++cs)
          sA[mi][ni] = __builtin_amdgcn_mfma_f32_16x16x32_bf16(qa[mi][cs], kf[ni][cs],
                                                               sA[mi][ni], 0, 0, 0);

    float sv[2][2][4];
#pragma unroll
    for (int mi = 0; mi < 2; ++mi)
#pragma unroll
      for (int ni = 0; ni < 2; ++ni)
#pragma unroll
        for (int r = 0; r < 4; ++r) {
          int q = qw0 + 16 * mi + 4 * g + r;
          int k = kt + 16 * ni + c;
          sv[mi][ni][r] = ((unsigned)(q - k) <= 256u) ? sA[mi][ni][r] * 0.125f : -3.0e38f;
        }

#pragma unroll
    for (int mi = 0; mi < 2; ++mi) {
#pragma unroll
      for (int r = 0; r < 4; ++r) {
        float tm = fmaxf(sv[mi][0][r], sv[mi][1][r]);
        tm = fmaxf(tm, __shfl_xor(tm, 1));
        tm = fmaxf(tm, __shfl_xor(tm, 2));
        tm = fmaxf(tm, __shfl_xor(tm, 4));
        tm = fmaxf(tm, __shfl_xor(tm, 8));
        float mnew = fmaxf(mrow[mi][r], tm);
        float sc = __expf(mrow[mi][r] - mnew);
        mrow[mi][r] = mnew;
        float p0 = __expf(sv[mi][0][r] - mnew);
        float p1 = __expf(sv[mi][1][r] - mnew);
        float ps = p0 + p1;
        ps += __shfl_xor(ps, 1);
        ps += __shfl_xor(ps, 2);
        ps += __shfl_xor(ps, 4);
        ps += __shfl_xor(ps, 8);
        lsum[mi][r] = lsum[mi][r] * sc + ps;
#pragma unroll
        for (int ni = 0; ni < 4; ++ni)
          o[mi][ni][r] *= sc;
        int qloc = 16 * mi + 4 * g + r;
        int xr = (qloc & 12) << 2;
        *(unsigned short*)(Pb + ((qloc * 64 + c * 2) ^ xr)) = f2bf(p0);
        *(unsigned short*)(Pb + ((qloc * 64 + 32 + c * 2) ^ xr)) = f2bf(p1);
      }
    }

#pragma unroll
    for (int mi = 0; mi < 2; ++mi) {
      int qloc = 16 * mi + c;
      short8 pa = *(const short8*)(Pb + ((qloc * 64 + g * 16) ^ ((qloc & 12) << 2)));
#pragma unroll
      for (int ni = 0; ni < 4; ++ni)
        o[mi][ni] = __builtin_amdgcn_mfma_f32_16x16x32_bf16(pa, vf[ni], o[mi][ni], 0, 0, 0);
    }

#pragma unroll
    for (int ni = 0; ni < 2; ++ni)
#pragma unroll
      for (int cs = 0; cs < 2; ++cs)
        kf[ni][cs] = kfn[ni][cs];
#pragma unroll
    for (int ni = 0; ni < 4; ++ni)
      vf[ni] = vfn[ni];
  }

#pragma unroll
  for (int mi = 0; mi < 2; ++mi)
#pragma unroll
    for (int r = 0; r < 4; ++r) {
      float inv = 1.f / lsum[mi][r];
      int q = qw0 + 16 * mi + 4 * g + r;
      unsigned short* row = AO + (size_t)(b * 2048 + q) * 1024 + h * 64 + c;
#pragma unroll
      for (int ni = 0; ni < 4; ++ni)
        row[16 * ni] = f2bf(o[mi][ni][r] * inv);
    }
}

extern "C" void kernel_launch(void* const* d_in, const int* in_sizes, int n_in,
                              void* d_out, int out_size, void* d_ws, size_t ws_size,
                              hipStream_t stream) {
  const float* X  = (const float*)d_in[0];
  const float* wq = (const float*)d_in[1];
  const float* bq = (const float*)d_in[2];
  const float* wk = (const float*)d_in[3];
  const float* bk = (const float*)d_in[4];
  const float* wv = (const float*)d_in[5];
  const float* bv = (const float*)d_in[6];
  const float* wo = (const float*)d_in[7];
  const float* bo = (const float*)d_in[8];
  float* out = (float*)d_out;

  // workspace (ushort elems): Xb[4194304] | Wb[4x1048576] | QKV[3x4194304] | AO[4194304]
  unsigned short* Xb  = (unsigned short*)d_ws;
  unsigned short* Wb  = Xb + 4194304;
  unsigned short* QKV = Wb + 4194304;
  unsigned short* AO  = QKV + 12582912;

  cvt4<<<dim3(4096), dim3(256), 0, stream>>>(X, Xb);
  cvt_w<<<dim3(1024, 1, 4), dim3(256), 0, stream>>>(wq, wk, wv, wo, Wb);
  // Q,K (swapped epilogue, packed d-dim stores)
  gemm_bt<0, true, 128><<<dim3(8, 32, 2), dim3(256), 0, stream>>>(
      Xb, Wb, bq, bk, QKV, nullptr);
  // V (unswapped, packed s-dim stores into [d][s])
  gemm_bt<0, false, 128><<<dim3(8, 32, 1), dim3(256), 0, stream>>>(
      Xb, Wb + 2 * 1048576, bv, bv, QKV, nullptr);
  attn_mfma<<<dim3(16, 16, 2), dim3(256), 0, stream>>>(QKV, AO);
  // O-proj: 128x64 tiles -> 512 blocks (2/CU), packed f32x4 stores
  gemm_bt<1, true, 64><<<dim3(16, 32, 1), dim3(256), 0, stream>>>(
      AO, Wb + 3 * 1048576, bo, bo, nullptr, out);
}

// Round 6
// 92.441 us; speedup vs baseline: 1.0663x; 1.0663x over previous
//
#include <hip/hip_runtime.h>
#include <hip/hip_bf16.h>
#include <stdint.h>

typedef __attribute__((ext_vector_type(8))) short short8;
typedef __attribute__((ext_vector_type(4))) float f32x4;
typedef __attribute__((ext_vector_type(4))) unsigned short u16x4;

__device__ __forceinline__ float bf2f(unsigned short u) {
  union { unsigned int u; float f; } x; x.u = ((unsigned int)u) << 16; return x.f;
}
__device__ __forceinline__ unsigned short f2bf(float f) {
  union { float f; unsigned int u; } x; x.f = f;
  unsigned int u = x.u;
  return (unsigned short)((u + 0x7fffu + ((u >> 16) & 1u)) >> 16);
}

__device__ __forceinline__ void gload_lds16(const void* g, void* l) {
  __builtin_amdgcn_global_load_lds(
      (const __attribute__((address_space(1))) void*)g,
      (__attribute__((address_space(3))) void*)l, 16, 0, 0);
}

// ---------------- fp32 -> bf16 convert (X + all 4 weights, one launch) ------
__global__ void cvt_all(const float* __restrict__ X,
                        const float* __restrict__ w0, const float* __restrict__ w1,
                        const float* __restrict__ w2, const float* __restrict__ w3,
                        unsigned short* __restrict__ Xb,
                        unsigned short* __restrict__ Wb) {
  if (blockIdx.y == 0) {
    int i = (blockIdx.x * 256 + threadIdx.x) * 4;
    f32x4 f = *(const f32x4*)(X + i);
    u16x4 o = { f2bf(f[0]), f2bf(f[1]), f2bf(f[2]), f2bf(f[3]) };
    *(u16x4*)(Xb + i) = o;
  } else {
    int wi = blockIdx.x >> 10;
    const float* s = wi == 0 ? w0 : wi == 1 ? w1 : wi == 2 ? w2 : w3;
    int j = ((blockIdx.x & 1023) * 256 + threadIdx.x) * 4;
    f32x4 f = *(const f32x4*)(s + j);
    u16x4 o = { f2bf(f[0]), f2bf(f[1]), f2bf(f[2]), f2bf(f[3]) };
    *(u16x4*)(Wb + ((size_t)wi << 20) + j) = o;
  }
}

// ---------------- NT bf16 GEMM body, 128xBN tile, BK=32, 3-buf ring ---------
// Counted-vmcnt pipeline: stage tile t+2 during compute of tile t.
// LDS chunk swizzle (both sides): source chunk and ds_read chunk XOR (row>>1)&3.
// SWAP=true: acc = mfma(Wfrag, Afrag) -> reg-dim walks the FEATURE dim ->
//            packed epilogue stores. SWAP=false (V): reg-dim walks tokens ->
//            packed s-dim stores into transposed [b][h][d][s].
template <int MODE, bool SWAP, int BN>
__device__ __forceinline__ void gemm_body(
    const unsigned short* __restrict__ A, const unsigned short* __restrict__ W,
    const float* __restrict__ bias, unsigned short* __restrict__ obf,
    float* __restrict__ of32, unsigned short* lds, int z) {
  const int K = 1024, NT = 32;
  constexpr int GX = 1024 / BN;
  constexpr int LB = BN / 64;
  constexpr int NWC = BN / 64;
  constexpr int NWR = 4 / NWC;
  constexpr int MS = 128 / NWR;
  constexpr int MR = MS / 16;
  constexpr int ASZ = 128 * 32, BSZ = BN * 32;

  constexpr int NWG = GX * 32;
  int flat = blockIdx.y * GX + blockIdx.x;
  int swz = (flat & 7) * (NWG / 8) + (flat >> 3);
  const int n0 = (swz % GX) * BN, m0 = (swz / GX) * 128;

  const int tid = threadIdx.x, lane = tid & 63, w = tid >> 6;
  const int wr = w / NWC, wc = w % NWC;
  const int fr = lane & 15, g = lane >> 4;

  f32x4 acc[MR][4] = {};

#define STAGE(bi, t)                                                            \
  do {                                                                          \
    unsigned short* lb = lds + (bi) * (ASZ + BSZ);                              \
    _Pragma("unroll") for (int i = 0; i < 2; ++i) {                             \
      int s = i * 256 + tid;                                                    \
      int row = s >> 2;                                                         \
      int gc = (s & 3) ^ ((row >> 1) & 3);                                      \
      gload_lds16(A + (size_t)(m0 + row) * K + (t) * 32 + gc * 8, &lb[s * 8]);  \
    }                                                                           \
    _Pragma("unroll") for (int i = 0; i < LB; ++i) {                            \
      int s = i * 256 + tid;                                                    \
      int row = s >> 2;                                                         \
      int gc = (s & 3) ^ ((row >> 1) & 3);                                      \
      gload_lds16(W + (size_t)(n0 + row) * K + (t) * 32 + gc * 8,               \
                  &lb[ASZ + s * 8]);                                            \
    }                                                                           \
  } while (0)

#define COMPUTE(bi)                                                             \
  do {                                                                          \
    unsigned short* lb = lds + (bi) * (ASZ + BSZ);                              \
    short8 af[MR], bfr[4];                                                      \
    _Pragma("unroll") for (int m = 0; m < MR; ++m) {                            \
      int ra = wr * MS + m * 16 + fr;                                           \
      af[m] = *(const short8*)&lb[ra * 32 + ((g ^ ((ra >> 1) & 3)) * 8)];       \
    }                                                                           \
    _Pragma("unroll") for (int n = 0; n < 4; ++n) {                             \
      int rb2 = wc * 64 + n * 16 + fr;                                          \
      bfr[n] = *(const short8*)&lb[ASZ + rb2 * 32 + ((g ^ ((rb2 >> 1) & 3)) * 8)]; \
    }                                                                           \
    _Pragma("unroll") for (int m = 0; m < MR; ++m)                              \
        _Pragma("unroll") for (int n = 0; n < 4; ++n) {                         \
      if constexpr (SWAP)                                                       \
        acc[m][n] = __builtin_amdgcn_mfma_f32_16x16x32_bf16(bfr[n], af[m],      \
                                                            acc[m][n], 0, 0, 0);\
      else                                                                      \
        acc[m][n] = __builtin_amdgcn_mfma_f32_16x16x32_bf16(af[m], bfr[n],      \
                                                            acc[m][n], 0, 0, 0);\
    }                                                                           \
  } while (0)

  STAGE(0, 0);
  STAGE(1, 1);
  for (int t = 0; t < NT; ++t) {
    if (t < NT - 1) {
      if constexpr (BN == 128)
        asm volatile("s_waitcnt vmcnt(4)" ::: "memory");
      else
        asm volatile("s_waitcnt vmcnt(3)" ::: "memory");
    } else {
      asm volatile("s_waitcnt vmcnt(0)" ::: "memory");
    }
    __builtin_amdgcn_s_barrier();
    __builtin_amdgcn_sched_barrier(0);
    if (t + 2 < NT) STAGE((t + 2) % 3, t + 2);
    __builtin_amdgcn_s_setprio(1);
    COMPUTE(t % 3);
    __builtin_amdgcn_s_setprio(0);
  }
#undef STAGE
#undef COMPUTE

  if constexpr (SWAP) {
#pragma unroll
    for (int m = 0; m < MR; ++m) {
#pragma unroll
      for (int n = 0; n < 4; ++n) {
        int token = m0 + wr * MS + m * 16 + fr;
        int col0 = n0 + wc * 64 + n * 16 + g * 4;
        f32x4 bv = *(const f32x4*)&bias[col0];
        if (MODE == 0) {
          u16x4 pk;
#pragma unroll
          for (int i = 0; i < 4; ++i) pk[i] = f2bf(acc[m][n][i] + bv[i]);
          int hh = col0 >> 6, d0 = col0 & 63;
          int bb = token >> 11, s0 = token & 2047;
          *(u16x4*)&obf[(((size_t)(z * 32 + bb * 16 + hh)) * 2048 + s0) * 64 + d0] = pk;
        } else {
          f32x4 o;
#pragma unroll
          for (int i = 0; i < 4; ++i) o[i] = acc[m][n][i] + bv[i];
          *(f32x4*)&of32[(size_t)token * 1024 + col0] = o;
        }
      }
    }
  } else {
#pragma unroll
    for (int m = 0; m < MR; ++m) {
#pragma unroll
      for (int n = 0; n < 4; ++n) {
        int col = n0 + wc * 64 + n * 16 + fr;
        float bias_v = bias[col];
        int row0 = m0 + wr * MS + m * 16 + g * 4;
        int hh = col >> 6, d = col & 63;
        int bb = row0 >> 11, s0 = row0 & 2047;
        u16x4 pk;
#pragma unroll
        for (int i = 0; i < 4; ++i) pk[i] = f2bf(acc[m][n][i] + bias_v);
        *(u16x4*)&obf[(((size_t)(64 + bb * 16 + hh)) * 64 + d) * 2048 + s0] = pk;
      }
    }
  }
}

// Single QKV launch: z in {0,1,2}; Q,K swapped epilogue; V unswapped (-> V^T).
__global__ __launch_bounds__(256)
void gemm_qkv(const unsigned short* __restrict__ A,
              const unsigned short* __restrict__ Wbase,
              const float* __restrict__ bq, const float* __restrict__ bk,
              const float* __restrict__ bv, unsigned short* __restrict__ obf) {
  __shared__ unsigned short lds[3 * 8192];
  const int z = blockIdx.z;
  const unsigned short* W = Wbase + ((size_t)z << 20);
  const float* bias = z == 0 ? bq : z == 1 ? bk : bv;
  if (z == 2)
    gemm_body<0, false, 128>(A, W, bias, obf, nullptr, lds, z);
  else
    gemm_body<0, true, 128>(A, W, bias, obf, nullptr, lds, z);
}

// O-projection: 128x64 tiles (512 blocks = 2/CU), packed f32x4 stores.
__global__ __launch_bounds__(256)
void gemm_oproj(const unsigned short* __restrict__ A,
                const unsigned short* __restrict__ W,
                const float* __restrict__ bo, float* __restrict__ out) {
  __shared__ unsigned short lds[3 * 6144];
  gemm_body<1, true, 64>(A, W, bo, nullptr, out, lds, 0);
}

// ---------------- MFMA flash attention, window=256 ----------------
__global__ __launch_bounds__(256)
void attn_mfma(const unsigned short* __restrict__ QKV, unsigned short* __restrict__ AO) {
  const int S = 2048;
  const int b = blockIdx.z, h = blockIdx.y;
  const int q0 = blockIdx.x * 128;
  const size_t hb = (size_t)(b * 16 + h);
  const unsigned short* Qh = QKV + hb * (S * 64);
  const unsigned short* Kh = QKV + 4194304 + hb * (S * 64);
  const unsigned short* Vt = QKV + 8388608 + hb * (S * 64);  // [64][2048]

  const int tid = threadIdx.x;
  const int lane = tid & 63, w = tid >> 6;
  const int c = lane & 15, g = lane >> 4;
  const int qw0 = q0 + 32 * w;

  __shared__ unsigned short Plds[4][1024];
  char* Pb = (char*)&Plds[w][0];

  short8 qa[2][2];
#pragma unroll
  for (int mi = 0; mi < 2; ++mi)
#pragma unroll
    for (int cs = 0; cs < 2; ++cs)
      qa[mi][cs] = *(const short8*)(Qh + (size_t)(qw0 + 16 * mi + c) * 64 + 32 * cs + g * 8);

  f32x4 o[2][4] = {};
  float mrow[2][4], lsum[2][4];
#pragma unroll
  for (int mi = 0; mi < 2; ++mi)
#pragma unroll
    for (int r = 0; r < 4; ++r) { mrow[mi][r] = -1e30f; lsum[mi][r] = 0.f; }

  int kt0 = qw0 - 256; if (kt0 < 0) kt0 = 0;
  const int ktlast = qw0;

  short8 kf[2][2], vf[4];
#pragma unroll
  for (int ni = 0; ni < 2; ++ni)
#pragma unroll
    for (int cs = 0; cs < 2; ++cs)
      kf[ni][cs] = *(const short8*)(Kh + (size_t)(kt0 + 16 * ni + c) * 64 + 32 * cs + g * 8);
#pragma unroll
  for (int ni = 0; ni < 4; ++ni)
    vf[ni] = *(const short8*)(Vt + (size_t)(16 * ni + c) * 2048 + kt0 + g * 8);

  for (int kt = kt0; kt <= ktlast; kt += 32) {
    const int ktn = (kt + 32 <= ktlast) ? kt + 32 : kt;
    short8 kfn[2][2], vfn[4];
#pragma unroll
    for (int ni = 0; ni < 2; ++ni)
#pragma unroll
      for (int cs = 0; cs < 2; ++cs)
        kfn[ni][cs] = *(const short8*)(Kh + (size_t)(ktn + 16 * ni + c) * 64 + 32 * cs + g * 8);
#pragma unroll
    for (int ni = 0; ni < 4; ++ni)
      vfn[ni] = *(const short8*)(Vt + (size_t)(16 * ni + c) * 2048 + ktn + g * 8);

    f32x4 sA[2][2] = {};
#pragma unroll
    for (int mi = 0; mi < 2; ++mi)
#pragma unroll
      for (int ni = 0; ni < 2; ++ni)
#pragma unroll
        for (int cs = 0; cs < 2; ++cs)
          sA[mi][ni] = __builtin_amdgcn_mfma_f32_16x16x32_bf16(qa[mi][cs], kf[ni][cs],
                                                               sA[mi][ni], 0, 0, 0);

    float sv[2][2][4];
#pragma unroll
    for (int mi = 0; mi < 2; ++mi)
#pragma unroll
      for (int ni = 0; ni < 2; ++ni)
#pragma unroll
        for (int r = 0; r < 4; ++r) {
          int q = qw0 + 16 * mi + 4 * g + r;
          int k = kt + 16 * ni + c;
          sv[mi][ni][r] = ((unsigned)(q - k) <= 256u) ? sA[mi][ni][r] * 0.125f : -3.0e38f;
        }

#pragma unroll
    for (int mi = 0; mi < 2; ++mi) {
#pragma unroll
      for (int r = 0; r < 4; ++r) {
        float tm = fmaxf(sv[mi][0][r], sv[mi][1][r]);
        tm = fmaxf(tm, __shfl_xor(tm, 1));
        tm = fmaxf(tm, __shfl_xor(tm, 2));
        tm = fmaxf(tm, __shfl_xor(tm, 4));
        tm = fmaxf(tm, __shfl_xor(tm, 8));
        float mnew = fmaxf(mrow[mi][r], tm);
        float sc = __expf(mrow[mi][r] - mnew);
        mrow[mi][r] = mnew;
        float p0 = __expf(sv[mi][0][r] - mnew);
        float p1 = __expf(sv[mi][1][r] - mnew);
        float ps = p0 + p1;
        ps += __shfl_xor(ps, 1);
        ps += __shfl_xor(ps, 2);
        ps += __shfl_xor(ps, 4);
        ps += __shfl_xor(ps, 8);
        lsum[mi][r] = lsum[mi][r] * sc + ps;
#pragma unroll
        for (int ni = 0; ni < 4; ++ni)
          o[mi][ni][r] *= sc;
        int qloc = 16 * mi + 4 * g + r;
        int xr = (qloc & 12) << 2;
        *(unsigned short*)(Pb + ((qloc * 64 + c * 2) ^ xr)) = f2bf(p0);
        *(unsigned short*)(Pb + ((qloc * 64 + 32 + c * 2) ^ xr)) = f2bf(p1);
      }
    }

#pragma unroll
    for (int mi = 0; mi < 2; ++mi) {
      int qloc = 16 * mi + c;
      short8 pa = *(const short8*)(Pb + ((qloc * 64 + g * 16) ^ ((qloc & 12) << 2)));
#pragma unroll
      for (int ni = 0; ni < 4; ++ni)
        o[mi][ni] = __builtin_amdgcn_mfma_f32_16x16x32_bf16(pa, vf[ni], o[mi][ni], 0, 0, 0);
    }

#pragma unroll
    for (int ni = 0; ni < 2; ++ni)
#pragma unroll
      for (int cs = 0; cs < 2; ++cs)
        kf[ni][cs] = kfn[ni][cs];
#pragma unroll
    for (int ni = 0; ni < 4; ++ni)
      vf[ni] = vfn[ni];
  }

#pragma unroll
  for (int mi = 0; mi < 2; ++mi)
#pragma unroll
    for (int r = 0; r < 4; ++r) {
      float inv = 1.f / lsum[mi][r];
      int q = qw0 + 16 * mi + 4 * g + r;
      unsigned short* row = AO + (size_t)(b * 2048 + q) * 1024 + h * 64 + c;
#pragma unroll
      for (int ni = 0; ni < 4; ++ni)
        row[16 * ni] = f2bf(o[mi][ni][r] * inv);
    }
}

extern "C" void kernel_launch(void* const* d_in, const int* in_sizes, int n_in,
                              void* d_out, int out_size, void* d_ws, size_t ws_size,
                              hipStream_t stream) {
  const float* X  = (const float*)d_in[0];
  const float* wq = (const float*)d_in[1];
  const float* bq = (const float*)d_in[2];
  const float* wk = (const float*)d_in[3];
  const float* bk = (const float*)d_in[4];
  const float* wv = (const float*)d_in[5];
  const float* bv = (const float*)d_in[6];
  const float* wo = (const float*)d_in[7];
  const float* bo = (const float*)d_in[8];
  float* out = (float*)d_out;

  // workspace (ushort elems): Xb[4194304] | Wb[4x1048576] | QKV[3x4194304] | AO[4194304]
  unsigned short* Xb  = (unsigned short*)d_ws;
  unsigned short* Wb  = Xb + 4194304;
  unsigned short* QKV = Wb + 4194304;
  unsigned short* AO  = QKV + 12582912;

  cvt_all<<<dim3(4096, 2), dim3(256), 0, stream>>>(X, wq, wk, wv, wo, Xb, Wb);
  gemm_qkv<<<dim3(8, 32, 3), dim3(256), 0, stream>>>(Xb, Wb, bq, bk, bv, QKV);
  attn_mfma<<<dim3(16, 16, 2), dim3(256), 0, stream>>>(QKV, AO);
  gemm_oproj<<<dim3(16, 32, 1), dim3(256), 0, stream>>>(AO, Wb + 3 * 1048576, bo, out);
}

// Round 7
// 89.568 us; speedup vs baseline: 1.1005x; 1.0321x over previous
//
#include <hip/hip_runtime.h>
#include <hip/hip_bf16.h>
#include <stdint.h>

typedef __attribute__((ext_vector_type(8))) short short8;
typedef __attribute__((ext_vector_type(4))) float f32x4;
typedef __attribute__((ext_vector_type(4))) unsigned short u16x4;

__device__ __forceinline__ float bf2f(unsigned short u) {
  union { unsigned int u; float f; } x; x.u = ((unsigned int)u) << 16; return x.f;
}
__device__ __forceinline__ unsigned short f2bf(float f) {
  union { float f; unsigned int u; } x; x.f = f;
  unsigned int u = x.u;
  return (unsigned short)((u + 0x7fffu + ((u >> 16) & 1u)) >> 16);
}

__device__ __forceinline__ void gload_lds16(const void* g, void* l) {
  __builtin_amdgcn_global_load_lds(
      (const __attribute__((address_space(1))) void*)g,
      (__attribute__((address_space(3))) void*)l, 16, 0, 0);
}

// ---------------- fp32 -> bf16 convert (X + all 4 weights, one launch) ------
__global__ void cvt_all(const float* __restrict__ X,
                        const float* __restrict__ w0, const float* __restrict__ w1,
                        const float* __restrict__ w2, const float* __restrict__ w3,
                        unsigned short* __restrict__ Xb,
                        unsigned short* __restrict__ Wb) {
  if (blockIdx.y == 0) {
    int i = (blockIdx.x * 256 + threadIdx.x) * 4;
    f32x4 f = *(const f32x4*)(X + i);
    u16x4 o = { f2bf(f[0]), f2bf(f[1]), f2bf(f[2]), f2bf(f[3]) };
    *(u16x4*)(Xb + i) = o;
  } else {
    int wi = blockIdx.x >> 10;
    const float* s = wi == 0 ? w0 : wi == 1 ? w1 : wi == 2 ? w2 : w3;
    int j = ((blockIdx.x & 1023) * 256 + threadIdx.x) * 4;
    f32x4 f = *(const f32x4*)(s + j);
    u16x4 o = { f2bf(f[0]), f2bf(f[1]), f2bf(f[2]), f2bf(f[3]) };
    *(u16x4*)(Wb + ((size_t)wi << 20) + j) = o;
  }
}

// ---------------- Fused QKV GEMM: one block computes Q,K,V tiles ------------
// 512 threads (8 waves: wr=w>>1 in 0..3 over 32-row spans, wc=w&1 over 64-col
// halves). Per K-tile: one shared A-stage (128x32) + 3 W-stages; 24 MFMA/wave.
// Triple-buffer ring, counted vmcnt, both-sides chunk swizzle.
// Q,K: swapped mfma (reg-dim walks feature) -> packed u16x4 into [z][b][h][s][d].
// V:   unswapped -> packed s-dim stores into transposed [b][h][d][s].
__global__ __launch_bounds__(512, 2)
void gemm_qkv_fused(const unsigned short* __restrict__ A,
                    const unsigned short* __restrict__ Wbase,
                    const float* __restrict__ bq, const float* __restrict__ bk,
                    const float* __restrict__ bv,
                    unsigned short* __restrict__ obf) {
  const int K = 1024, NT = 32;
  constexpr int ASZ = 128 * 32;        // 4096 ushorts
  constexpr int BSZ = 3 * 128 * 32;    // 12288 ushorts
  __shared__ unsigned short lds[3 * (ASZ + BSZ)];  // 96 KB

  // XCD-aware bijective swizzle: nwg = 256.
  int flat = blockIdx.y * 8 + blockIdx.x;
  int swz = (flat & 7) * 32 + (flat >> 3);
  const int n0 = (swz & 7) * 128, m0 = (swz >> 3) * 128;

  const int tid = threadIdx.x, lane = tid & 63, w = tid >> 6;
  const int wr = w >> 1, wc = w & 1;
  const int fr = lane & 15, g = lane >> 4;

  f32x4 acc[3][2][4] = {};

#define STAGE(bi, t)                                                            \
  do {                                                                          \
    unsigned short* lb = lds + (bi) * (ASZ + BSZ);                              \
    {                                                                           \
      int s = tid;                                                              \
      int row = s >> 2;                                                         \
      int gc = (s & 3) ^ ((row >> 1) & 3);                                      \
      gload_lds16(A + (size_t)(m0 + row) * K + (t) * 32 + gc * 8, &lb[s * 8]);  \
    }                                                                           \
    _Pragma("unroll") for (int i = 0; i < 3; ++i) {                             \
      int s = i * 512 + tid;                                                    \
      int row = s >> 2;          /* global B row: z*128 + local */              \
      int zz = row >> 7, br = row & 127;                                        \
      int gc = (s & 3) ^ ((row >> 1) & 3);                                      \
      gload_lds16(Wbase + ((size_t)zz << 20) + (size_t)(n0 + br) * K +          \
                      (t) * 32 + gc * 8,                                        \
                  &lb[ASZ + s * 8]);                                            \
    }                                                                           \
  } while (0)

#define COMPUTE(bi)                                                             \
  do {                                                                          \
    unsigned short* lb = lds + (bi) * (ASZ + BSZ);                              \
    short8 af[2], bfr[3][4];                                                    \
    _Pragma("unroll") for (int m = 0; m < 2; ++m) {                             \
      int ra = wr * 32 + m * 16 + fr;                                           \
      af[m] = *(const short8*)&lb[ra * 32 + ((g ^ ((ra >> 1) & 3)) * 8)];       \
    }                                                                           \
    _Pragma("unroll") for (int zz = 0; zz < 3; ++zz)                            \
        _Pragma("unroll") for (int n = 0; n < 4; ++n) {                         \
      int rb2 = zz * 128 + wc * 64 + n * 16 + fr;                               \
      bfr[zz][n] =                                                              \
          *(const short8*)&lb[ASZ + rb2 * 32 + ((g ^ ((rb2 >> 1) & 3)) * 8)];   \
    }                                                                           \
    _Pragma("unroll") for (int zz = 0; zz < 3; ++zz)                            \
        _Pragma("unroll") for (int m = 0; m < 2; ++m)                           \
        _Pragma("unroll") for (int n = 0; n < 4; ++n) {                         \
      if (zz < 2)                                                               \
        acc[zz][m][n] = __builtin_amdgcn_mfma_f32_16x16x32_bf16(                \
            bfr[zz][n], af[m], acc[zz][m][n], 0, 0, 0);                         \
      else                                                                      \
        acc[zz][m][n] = __builtin_amdgcn_mfma_f32_16x16x32_bf16(                \
            af[m], bfr[zz][n], acc[zz][m][n], 0, 0, 0);                         \
    }                                                                           \
  } while (0)

  STAGE(0, 0);
  STAGE(1, 1);
  for (int t = 0; t < NT; ++t) {
    if (t < NT - 1)
      asm volatile("s_waitcnt vmcnt(4)" ::: "memory");
    else
      asm volatile("s_waitcnt vmcnt(0)" ::: "memory");
    __builtin_amdgcn_s_barrier();
    __builtin_amdgcn_sched_barrier(0);
    if (t + 2 < NT) STAGE((t + 2) % 3, t + 2);
    __builtin_amdgcn_s_setprio(1);
    COMPUTE(t % 3);
    __builtin_amdgcn_s_setprio(0);
  }
#undef STAGE
#undef COMPUTE

  // epilogue: Q,K swapped (reg-dim walks feature d); V unswapped (walks s)
#pragma unroll
  for (int zz = 0; zz < 2; ++zz) {
    const float* bias = zz == 0 ? bq : bk;
#pragma unroll
    for (int m = 0; m < 2; ++m) {
#pragma unroll
      for (int n = 0; n < 4; ++n) {
        int token = m0 + wr * 32 + m * 16 + fr;
        int col0 = n0 + wc * 64 + n * 16 + g * 4;
        f32x4 bvv = *(const f32x4*)&bias[col0];
        u16x4 pk;
#pragma unroll
        for (int i = 0; i < 4; ++i) pk[i] = f2bf(acc[zz][m][n][i] + bvv[i]);
        int hh = col0 >> 6, d0 = col0 & 63;
        int bb = token >> 11, s0 = token & 2047;
        *(u16x4*)&obf[(((size_t)(zz * 32 + bb * 16 + hh)) * 2048 + s0) * 64 + d0] = pk;
      }
    }
  }
#pragma unroll
  for (int m = 0; m < 2; ++m) {
#pragma unroll
    for (int n = 0; n < 4; ++n) {
      int col = n0 + wc * 64 + n * 16 + fr;
      float bias_v = bv[col];
      int row0 = m0 + wr * 32 + m * 16 + g * 4;
      int hh = col >> 6, d = col & 63;
      int bb = row0 >> 11, s0 = row0 & 2047;
      u16x4 pk;
#pragma unroll
      for (int i = 0; i < 4; ++i) pk[i] = f2bf(acc[2][m][n][i] + bias_v);
      *(u16x4*)&obf[(((size_t)(64 + bb * 16 + hh)) * 64 + d) * 2048 + s0] = pk;
    }
  }
}

// ---------------- O-proj GEMM body (128x64 tile, BK=32, 3-buf ring) ---------
__global__ __launch_bounds__(256)
void gemm_oproj(const unsigned short* __restrict__ A,
                const unsigned short* __restrict__ W,
                const float* __restrict__ bias, float* __restrict__ of32) {
  const int K = 1024, NT = 32;
  constexpr int BN = 64;
  constexpr int GX = 1024 / BN;
  constexpr int ASZ = 128 * 32, BSZ = BN * 32;
  __shared__ unsigned short lds[3 * (ASZ + BSZ)];

  constexpr int NWG = GX * 32;
  int flat = blockIdx.y * GX + blockIdx.x;
  int swz = (flat & 7) * (NWG / 8) + (flat >> 3);
  const int n0 = (swz % GX) * BN, m0 = (swz / GX) * 128;

  const int tid = threadIdx.x, lane = tid & 63, w = tid >> 6;
  const int fr = lane & 15, g = lane >> 4;

  f32x4 acc[2][4] = {};

#define STAGE(bi, t)                                                            \
  do {                                                                          \
    unsigned short* lb = lds + (bi) * (ASZ + BSZ);                              \
    _Pragma("unroll") for (int i = 0; i < 2; ++i) {                             \
      int s = i * 256 + tid;                                                    \
      int row = s >> 2;                                                         \
      int gc = (s & 3) ^ ((row >> 1) & 3);                                      \
      gload_lds16(A + (size_t)(m0 + row) * K + (t) * 32 + gc * 8, &lb[s * 8]);  \
    }                                                                           \
    {                                                                           \
      int s = tid;                                                              \
      int row = s >> 2;                                                         \
      int gc = (s & 3) ^ ((row >> 1) & 3);                                      \
      gload_lds16(W + (size_t)(n0 + row) * K + (t) * 32 + gc * 8,               \
                  &lb[ASZ + s * 8]);                                            \
    }                                                                           \
  } while (0)

#define COMPUTE(bi)                                                             \
  do {                                                                          \
    unsigned short* lb = lds + (bi) * (ASZ + BSZ);                              \
    short8 af[2], bfr[4];                                                       \
    _Pragma("unroll") for (int m = 0; m < 2; ++m) {                             \
      int ra = w * 32 + m * 16 + fr;                                            \
      af[m] = *(const short8*)&lb[ra * 32 + ((g ^ ((ra >> 1) & 3)) * 8)];       \
    }                                                                           \
    _Pragma("unroll") for (int n = 0; n < 4; ++n) {                             \
      int rb2 = n * 16 + fr;                                                    \
      bfr[n] = *(const short8*)&lb[ASZ + rb2 * 32 + ((g ^ ((rb2 >> 1) & 3)) * 8)]; \
    }                                                                           \
    _Pragma("unroll") for (int m = 0; m < 2; ++m)                               \
        _Pragma("unroll") for (int n = 0; n < 4; ++n)                           \
        acc[m][n] = __builtin_amdgcn_mfma_f32_16x16x32_bf16(bfr[n], af[m],      \
                                                            acc[m][n], 0, 0, 0);\
  } while (0)

  STAGE(0, 0);
  STAGE(1, 1);
  for (int t = 0; t < NT; ++t) {
    if (t < NT - 1)
      asm volatile("s_waitcnt vmcnt(3)" ::: "memory");
    else
      asm volatile("s_waitcnt vmcnt(0)" ::: "memory");
    __builtin_amdgcn_s_barrier();
    __builtin_amdgcn_sched_barrier(0);
    if (t + 2 < NT) STAGE((t + 2) % 3, t + 2);
    __builtin_amdgcn_s_setprio(1);
    COMPUTE(t % 3);
    __builtin_amdgcn_s_setprio(0);
  }
#undef STAGE
#undef COMPUTE

#pragma unroll
  for (int m = 0; m < 2; ++m) {
#pragma unroll
    for (int n = 0; n < 4; ++n) {
      int token = m0 + w * 32 + m * 16 + fr;
      int col0 = n0 + n * 16 + g * 4;
      f32x4 bvv = *(const f32x4*)&bias[col0];
      f32x4 o;
#pragma unroll
      for (int i = 0; i < 4; ++i) o[i] = acc[m][n][i] + bvv[i];
      *(f32x4*)&of32[(size_t)token * 1024 + col0] = o;
    }
  }
}

// ---------------- MFMA flash attention, window=256 ----------------
__global__ __launch_bounds__(256)
void attn_mfma(const unsigned short* __restrict__ QKV, unsigned short* __restrict__ AO) {
  const int S = 2048;
  const int b = blockIdx.z, h = blockIdx.y;
  const int q0 = blockIdx.x * 128;
  const size_t hb = (size_t)(b * 16 + h);
  const unsigned short* Qh = QKV + hb * (S * 64);
  const unsigned short* Kh = QKV + 4194304 + hb * (S * 64);
  const unsigned short* Vt = QKV + 8388608 + hb * (S * 64);  // [64][2048]

  const int tid = threadIdx.x;
  const int lane = tid & 63, w = tid >> 6;
  const int c = lane & 15, g = lane >> 4;
  const int qw0 = q0 + 32 * w;

  __shared__ unsigned short Plds[4][1024];
  char* Pb = (char*)&Plds[w][0];

  short8 qa[2][2];
#pragma unroll
  for (int mi = 0; mi < 2; ++mi)
#pragma unroll
    for (int cs = 0; cs < 2; ++cs)
      qa[mi][cs] = *(const short8*)(Qh + (size_t)(qw0 + 16 * mi + c) * 64 + 32 * cs + g * 8);

  f32x4 o[2][4] = {};
  float mrow[2][4], lsum[2][4];
#pragma unroll
  for (int mi = 0; mi < 2; ++mi)
#pragma unroll
    for (int r = 0; r < 4; ++r) { mrow[mi][r] = -1e30f; lsum[mi][r] = 0.f; }

  int kt0 = qw0 - 256; if (kt0 < 0) kt0 = 0;
  const int ktlast = qw0;

  short8 kf[2][2], vf[4];
#pragma unroll
  for (int ni = 0; ni < 2; ++ni)
#pragma unroll
    for (int cs = 0; cs < 2; ++cs)
      kf[ni][cs] = *(const short8*)(Kh + (size_t)(kt0 + 16 * ni + c) * 64 + 32 * cs + g * 8);
#pragma unroll
  for (int ni = 0; ni < 4; ++ni)
    vf[ni] = *(const short8*)(Vt + (size_t)(16 * ni + c) * 2048 + kt0 + g * 8);

  for (int kt = kt0; kt <= ktlast; kt += 32) {
    const int ktn = (kt + 32 <= ktlast) ? kt + 32 : kt;
    short8 kfn[2][2], vfn[4];
#pragma unroll
    for (int ni = 0; ni < 2; ++ni)
#pragma unroll
      for (int cs = 0; cs < 2; ++cs)
        kfn[ni][cs] = *(const short8*)(Kh + (size_t)(ktn + 16 * ni + c) * 64 + 32 * cs + g * 8);
#pragma unroll
    for (int ni = 0; ni < 4; ++ni)
      vfn[ni] = *(const short8*)(Vt + (size_t)(16 * ni + c) * 2048 + ktn + g * 8);

    f32x4 sA[2][2] = {};
#pragma unroll
    for (int mi = 0; mi < 2; ++mi)
#pragma unroll
      for (int ni = 0; ni < 2; ++ni)
#pragma unroll
        for (int cs = 0; cs < 2; ++cs)
          sA[mi][ni] = __builtin_amdgcn_mfma_f32_16x16x32_bf16(qa[mi][cs], kf[ni][cs],
                                                               sA[mi][ni], 0, 0, 0);

    float sv[2][2][4];
#pragma unroll
    for (int mi = 0; mi < 2; ++mi)
#pragma unroll
      for (int ni = 0; ni < 2; ++ni)
#pragma unroll
        for (int r = 0; r < 4; ++r) {
          int q = qw0 + 16 * mi + 4 * g + r;
          int k = kt + 16 * ni + c;
          sv[mi][ni][r] = ((unsigned)(q - k) <= 256u) ? sA[mi][ni][r] * 0.125f : -3.0e38f;
        }

#pragma unroll
    for (int mi = 0; mi < 2; ++mi) {
#pragma unroll
      for (int r = 0; r < 4; ++r) {
        float tm = fmaxf(sv[mi][0][r], sv[mi][1][r]);
        tm = fmaxf(tm, __shfl_xor(tm, 1));
        tm = fmaxf(tm, __shfl_xor(tm, 2));
        tm = fmaxf(tm, __shfl_xor(tm, 4));
        tm = fmaxf(tm, __shfl_xor(tm, 8));
        float mnew = fmaxf(mrow[mi][r], tm);
        float sc = __expf(mrow[mi][r] - mnew);
        mrow[mi][r] = mnew;
        float p0 = __expf(sv[mi][0][r] - mnew);
        float p1 = __expf(sv[mi][1][r] - mnew);
        float ps = p0 + p1;
        ps += __shfl_xor(ps, 1);
        ps += __shfl_xor(ps, 2);
        ps += __shfl_xor(ps, 4);
        ps += __shfl_xor(ps, 8);
        lsum[mi][r] = lsum[mi][r] * sc + ps;
#pragma unroll
        for (int ni = 0; ni < 4; ++ni)
          o[mi][ni][r] *= sc;
        int qloc = 16 * mi + 4 * g + r;
        int xr = (qloc & 12) << 2;
        *(unsigned short*)(Pb + ((qloc * 64 + c * 2) ^ xr)) = f2bf(p0);
        *(unsigned short*)(Pb + ((qloc * 64 + 32 + c * 2) ^ xr)) = f2bf(p1);
      }
    }

#pragma unroll
    for (int mi = 0; mi < 2; ++mi) {
      int qloc = 16 * mi + c;
      short8 pa = *(const short8*)(Pb + ((qloc * 64 + g * 16) ^ ((qloc & 12) << 2)));
#pragma unroll
      for (int ni = 0; ni < 4; ++ni)
        o[mi][ni] = __builtin_amdgcn_mfma_f32_16x16x32_bf16(pa, vf[ni], o[mi][ni], 0, 0, 0);
    }

#pragma unroll
    for (int ni = 0; ni < 2; ++ni)
#pragma unroll
      for (int cs = 0; cs < 2; ++cs)
        kf[ni][cs] = kfn[ni][cs];
#pragma unroll
    for (int ni = 0; ni < 4; ++ni)
      vf[ni] = vfn[ni];
  }

#pragma unroll
  for (int mi = 0; mi < 2; ++mi)
#pragma unroll
    for (int r = 0; r < 4; ++r) {
      float inv = 1.f / lsum[mi][r];
      int q = qw0 + 16 * mi + 4 * g + r;
      unsigned short* row = AO + (size_t)(b * 2048 + q) * 1024 + h * 64 + c;
#pragma unroll
      for (int ni = 0; ni < 4; ++ni)
        row[16 * ni] = f2bf(o[mi][ni][r] * inv);
    }
}

extern "C" void kernel_launch(void* const* d_in, const int* in_sizes, int n_in,
                              void* d_out, int out_size, void* d_ws, size_t ws_size,
                              hipStream_t stream) {
  const float* X  = (const float*)d_in[0];
  const float* wq = (const float*)d_in[1];
  const float* bq = (const float*)d_in[2];
  const float* wk = (const float*)d_in[3];
  const float* bk = (const float*)d_in[4];
  const float* wv = (const float*)d_in[5];
  const float* bv = (const float*)d_in[6];
  const float* wo = (const float*)d_in[7];
  const float* bo = (const float*)d_in[8];
  float* out = (float*)d_out;

  // workspace (ushort elems): Xb[4194304] | Wb[4x1048576] | QKV[3x4194304] | AO[4194304]
  unsigned short* Xb  = (unsigned short*)d_ws;
  unsigned short* Wb  = Xb + 4194304;
  unsigned short* QKV = Wb + 4194304;
  unsigned short* AO  = QKV + 12582912;

  cvt_all<<<dim3(4096, 2), dim3(256), 0, stream>>>(X, wq, wk, wv, wo, Xb, Wb);
  gemm_qkv_fused<<<dim3(8, 32), dim3(512), 0, stream>>>(Xb, Wb, bq, bk, bv, QKV);
  attn_mfma<<<dim3(16, 16, 2), dim3(256), 0, stream>>>(QKV, AO);
  gemm_oproj<<<dim3(16, 32, 1), dim3(256), 0, stream>>>(AO, Wb + 3 * 1048576, bo, out);
}

// Round 8
// 86.311 us; speedup vs baseline: 1.1420x; 1.0377x over previous
//
#include <hip/hip_runtime.h>
#include <hip/hip_bf16.h>
#include <stdint.h>

typedef __attribute__((ext_vector_type(8))) short short8;
typedef __attribute__((ext_vector_type(4))) float f32x4;
typedef __attribute__((ext_vector_type(4))) unsigned short u16x4;

__device__ __forceinline__ float bf2f(unsigned short u) {
  union { unsigned int u; float f; } x; x.u = ((unsigned int)u) << 16; return x.f;
}
__device__ __forceinline__ unsigned short f2bf(float f) {
  union { float f; unsigned int u; } x; x.f = f;
  unsigned int u = x.u;
  return (unsigned short)((u + 0x7fffu + ((u >> 16) & 1u)) >> 16);
}

__device__ __forceinline__ void gload_lds16(const void* g, void* l) {
  __builtin_amdgcn_global_load_lds(
      (const __attribute__((address_space(1))) void*)g,
      (__attribute__((address_space(3))) void*)l, 16, 0, 0);
}

// ---------------- fp32 -> bf16 convert (X + all 4 weights, one launch) ------
__global__ void cvt_all(const float* __restrict__ X,
                        const float* __restrict__ w0, const float* __restrict__ w1,
                        const float* __restrict__ w2, const float* __restrict__ w3,
                        unsigned short* __restrict__ Xb,
                        unsigned short* __restrict__ Wb) {
  if (blockIdx.y == 0) {
    int i = (blockIdx.x * 256 + threadIdx.x) * 4;
    f32x4 f = *(const f32x4*)(X + i);
    u16x4 o = { f2bf(f[0]), f2bf(f[1]), f2bf(f[2]), f2bf(f[3]) };
    *(u16x4*)(Xb + i) = o;
  } else {
    int wi = blockIdx.x >> 10;
    const float* s = wi == 0 ? w0 : wi == 1 ? w1 : wi == 2 ? w2 : w3;
    int j = ((blockIdx.x & 1023) * 256 + threadIdx.x) * 4;
    f32x4 f = *(const f32x4*)(s + j);
    u16x4 o = { f2bf(f[0]), f2bf(f[1]), f2bf(f[2]), f2bf(f[3]) };
    *(u16x4*)(Wb + ((size_t)wi << 20) + j) = o;
  }
}

// ---------------- Fused QKV GEMM, fine-interleaved phases -------------------
// 512 threads (8 waves). Per K-tile: 3 MFMA clusters of 8 (one per z), with
// the 4 stage-loads of tile t+2 distributed between clusters. Ring-3,
// counted vmcnt(4), both-sides chunk swizzle.
__global__ __launch_bounds__(512, 2)
void gemm_qkv_fused(const unsigned short* __restrict__ A,
                    const unsigned short* __restrict__ Wbase,
                    const float* __restrict__ bq, const float* __restrict__ bk,
                    const float* __restrict__ bv,
                    unsigned short* __restrict__ obf) {
  const int K = 1024, NT = 32;
  constexpr int ASZ = 128 * 32;        // 4096 ushorts
  constexpr int BSZ = 3 * 128 * 32;    // 12288 ushorts
  __shared__ unsigned short lds[3 * (ASZ + BSZ)];  // 96 KB

  int flat = blockIdx.y * 8 + blockIdx.x;
  int swz = (flat & 7) * 32 + (flat >> 3);
  const int n0 = (swz & 7) * 128, m0 = (swz >> 3) * 128;

  const int tid = threadIdx.x, lane = tid & 63, w = tid >> 6;
  const int wr = w >> 1, wc = w & 1;
  const int fr = lane & 15, g = lane >> 4;

  f32x4 acc[3][2][4] = {};

#define STAGE_A(bi, t)                                                          \
  do {                                                                          \
    int s = tid;                                                                \
    int row = s >> 2;                                                           \
    int gc = (s & 3) ^ ((row >> 1) & 3);                                        \
    gload_lds16(A + (size_t)(m0 + row) * K + (t) * 32 + gc * 8,                 \
                &lds[(bi) * (ASZ + BSZ) + s * 8]);                              \
  } while (0)

#define STAGE_W(bi, t, i)                                                       \
  do {                                                                          \
    int s = (i) * 512 + tid;                                                    \
    int row = s >> 2;                                                           \
    int zz = row >> 7, br = row & 127;                                          \
    int gc = (s & 3) ^ ((row >> 1) & 3);                                        \
    gload_lds16(Wbase + ((size_t)zz << 20) + (size_t)(n0 + br) * K +            \
                    (t) * 32 + gc * 8,                                          \
                &lds[(bi) * (ASZ + BSZ) + ASZ + s * 8]);                        \
  } while (0)

  // prologue: tiles 0 and 1 fully staged
  STAGE_A(0, 0); STAGE_W(0, 0, 0); STAGE_W(0, 0, 1); STAGE_W(0, 0, 2);
  STAGE_A(1, 1); STAGE_W(1, 1, 0); STAGE_W(1, 1, 1); STAGE_W(1, 1, 2);

  for (int t = 0; t < NT; ++t) {
    if (t < NT - 1)
      asm volatile("s_waitcnt vmcnt(4)" ::: "memory");
    else
      asm volatile("s_waitcnt vmcnt(0)" ::: "memory");
    __builtin_amdgcn_s_barrier();
    __builtin_amdgcn_sched_barrier(0);

    const int bi = t % 3, bi2 = (t + 2) % 3;
    const bool pf = (t + 2 < NT);
    unsigned short* lb = lds + bi * (ASZ + BSZ);

    if (pf) STAGE_A(bi2, t + 2);

    short8 af[2];
#pragma unroll
    for (int m = 0; m < 2; ++m) {
      int ra = wr * 32 + m * 16 + fr;
      af[m] = *(const short8*)&lb[ra * 32 + ((g ^ ((ra >> 1) & 3)) * 8)];
    }

#pragma unroll
    for (int zz = 0; zz < 3; ++zz) {
      short8 bfr[4];
#pragma unroll
      for (int n = 0; n < 4; ++n) {
        int rb2 = zz * 128 + wc * 64 + n * 16 + fr;
        bfr[n] = *(const short8*)&lb[ASZ + rb2 * 32 + ((g ^ ((rb2 >> 1) & 3)) * 8)];
      }
      if (pf) STAGE_W(bi2, t + 2, zz);
      __builtin_amdgcn_s_setprio(1);
#pragma unroll
      for (int m = 0; m < 2; ++m)
#pragma unroll
        for (int n = 0; n < 4; ++n) {
          if (zz < 2)
            acc[zz][m][n] = __builtin_amdgcn_mfma_f32_16x16x32_bf16(
                bfr[n], af[m], acc[zz][m][n], 0, 0, 0);
          else
            acc[zz][m][n] = __builtin_amdgcn_mfma_f32_16x16x32_bf16(
                af[m], bfr[n], acc[zz][m][n], 0, 0, 0);
        }
      __builtin_amdgcn_s_setprio(0);
    }
  }
#undef STAGE_A
#undef STAGE_W

  // epilogue: Q,K swapped (reg-dim walks feature d); V unswapped (walks s)
#pragma unroll
  for (int zz = 0; zz < 2; ++zz) {
    const float* bias = zz == 0 ? bq : bk;
#pragma unroll
    for (int m = 0; m < 2; ++m) {
#pragma unroll
      for (int n = 0; n < 4; ++n) {
        int token = m0 + wr * 32 + m * 16 + fr;
        int col0 = n0 + wc * 64 + n * 16 + g * 4;
        f32x4 bvv = *(const f32x4*)&bias[col0];
        u16x4 pk;
#pragma unroll
        for (int i = 0; i < 4; ++i) pk[i] = f2bf(acc[zz][m][n][i] + bvv[i]);
        int hh = col0 >> 6, d0 = col0 & 63;
        int bb = token >> 11, s0 = token & 2047;
        *(u16x4*)&obf[(((size_t)(zz * 32 + bb * 16 + hh)) * 2048 + s0) * 64 + d0] = pk;
      }
    }
  }
#pragma unroll
  for (int m = 0; m < 2; ++m) {
#pragma unroll
    for (int n = 0; n < 4; ++n) {
      int col = n0 + wc * 64 + n * 16 + fr;
      float bias_v = bv[col];
      int row0 = m0 + wr * 32 + m * 16 + g * 4;
      int hh = col >> 6, d = col & 63;
      int bb = row0 >> 11, s0 = row0 & 2047;
      u16x4 pk;
#pragma unroll
      for (int i = 0; i < 4; ++i) pk[i] = f2bf(acc[2][m][n][i] + bias_v);
      *(u16x4*)&obf[(((size_t)(64 + bb * 16 + hh)) * 64 + d) * 2048 + s0] = pk;
    }
  }
}

// ---------------- O-proj: 128x128 tile, 8 waves, wave-level K-split ---------
// BK=64 staged tile shared by two K-groups (waves 0-3: k 0-31; 4-7: k 32-63).
// Each wave: 64x64 output quadrant, 16 MFMA per K-tile, 8 ds_read_b128.
// Ring-3 (96 KB), counted vmcnt(4). Final in-LDS f32 reduce across K-groups.
__global__ __launch_bounds__(512, 2)
void gemm_oproj(const unsigned short* __restrict__ A,
                const unsigned short* __restrict__ W,
                const float* __restrict__ bias, float* __restrict__ of32) {
  const int K = 1024, NT = 16;
  constexpr int ABUF = 128 * 64;       // 8192 ushorts
  constexpr int BUFSZ = 2 * ABUF;      // 16384 ushorts = 32 KB
  __shared__ unsigned short lds[3 * BUFSZ];  // 96 KB

  int flat = blockIdx.y * 8 + blockIdx.x;
  int swz = (flat & 7) * 32 + (flat >> 3);
  const int n0 = (swz & 7) * 128, m0 = (swz >> 3) * 128;

  const int tid = threadIdx.x, lane = tid & 63, w = tid >> 6;
  const int kg = w >> 2, wq = w & 3;
  const int mt = (wq >> 1) * 64, nt = (wq & 1) * 64;
  const int fr = lane & 15, g = lane >> 4;

  f32x4 acc[4][4] = {};

  // chunk swizzle: global k-chunk kc stored at slot kc ^ (row & 7)
#define STAGE(bi, t)                                                            \
  do {                                                                          \
    unsigned short* lb = lds + (bi) * BUFSZ;                                    \
    _Pragma("unroll") for (int i = 0; i < 2; ++i) {                             \
      int c = i * 512 + tid;                                                    \
      int row = c >> 3;                                                         \
      int ch = (c & 7) ^ (row & 7);                                             \
      gload_lds16(A + (size_t)(m0 + row) * K + (t) * 64 + ch * 8, &lb[c * 8]);  \
    }                                                                           \
    _Pragma("unroll") for (int i = 0; i < 2; ++i) {                             \
      int c = i * 512 + tid;                                                    \
      int row = c >> 3;                                                         \
      int ch = (c & 7) ^ (row & 7);                                             \
      gload_lds16(W + (size_t)(n0 + row) * K + (t) * 64 + ch * 8,               \
                  &lb[ABUF + c * 8]);                                           \
    }                                                                           \
  } while (0)

  STAGE(0, 0);
  STAGE(1, 1);
  const int kc = kg * 4 + g;  // this lane's k-chunk within the 64-k tile
  for (int t = 0; t < NT; ++t) {
    if (t < NT - 1)
      asm volatile("s_waitcnt vmcnt(4)" ::: "memory");
    else
      asm volatile("s_waitcnt vmcnt(0)" ::: "memory");
    __builtin_amdgcn_s_barrier();
    __builtin_amdgcn_sched_barrier(0);
    if (t + 2 < NT) STAGE((t + 2) % 3, t + 2);

    unsigned short* lb = lds + (t % 3) * BUFSZ;
    short8 af[4], bf[4];
#pragma unroll
    for (int m = 0; m < 4; ++m) {
      int ra = mt + m * 16 + fr;
      af[m] = *(const short8*)&lb[ra * 64 + ((kc ^ (ra & 7)) * 8)];
    }
#pragma unroll
    for (int n = 0; n < 4; ++n) {
      int rb = nt + n * 16 + fr;
      bf[n] = *(const short8*)&lb[ABUF + rb * 64 + ((kc ^ (rb & 7)) * 8)];
    }
    __builtin_amdgcn_s_setprio(1);
#pragma unroll
    for (int m = 0; m < 4; ++m)
#pragma unroll
      for (int n = 0; n < 4; ++n)
        acc[m][n] = __builtin_amdgcn_mfma_f32_16x16x32_bf16(bf[n], af[m],
                                                            acc[m][n], 0, 0, 0);
    __builtin_amdgcn_s_setprio(0);
  }
#undef STAGE

  // cross-K-group reduce through LDS (all staging traffic has drained)
  __syncthreads();
  float* red = (float*)lds;  // need 4 waves * 16KB = 64 KB <= 96 KB
  if (kg == 1) {
#pragma unroll
    for (int m = 0; m < 4; ++m)
#pragma unroll
      for (int n = 0; n < 4; ++n)
        *(f32x4*)(red + wq * 4096 + (m * 4 + n) * 256 + lane * 4) = acc[m][n];
  }
  __syncthreads();
  if (kg == 0) {
#pragma unroll
    for (int m = 0; m < 4; ++m) {
#pragma unroll
      for (int n = 0; n < 4; ++n) {
        f32x4 other = *(const f32x4*)(red + wq * 4096 + (m * 4 + n) * 256 + lane * 4);
        int token = m0 + mt + m * 16 + fr;
        int col0 = n0 + nt + n * 16 + g * 4;
        f32x4 bvv = *(const f32x4*)&bias[col0];
        f32x4 o;
#pragma unroll
        for (int i = 0; i < 4; ++i) o[i] = acc[m][n][i] + other[i] + bvv[i];
        *(f32x4*)&of32[(size_t)token * 1024 + col0] = o;
      }
    }
  }
}

// ---------------- MFMA flash attention, window=256 ----------------
__global__ __launch_bounds__(256)
void attn_mfma(const unsigned short* __restrict__ QKV, unsigned short* __restrict__ AO) {
  const int S = 2048;
  const int b = blockIdx.z, h = blockIdx.y;
  const int q0 = blockIdx.x * 128;
  const size_t hb = (size_t)(b * 16 + h);
  const unsigned short* Qh = QKV + hb * (S * 64);
  const unsigned short* Kh = QKV + 4194304 + hb * (S * 64);
  const unsigned short* Vt = QKV + 8388608 + hb * (S * 64);  // [64][2048]

  const int tid = threadIdx.x;
  const int lane = tid & 63, w = tid >> 6;
  const int c = lane & 15, g = lane >> 4;
  const int qw0 = q0 + 32 * w;

  __shared__ unsigned short Plds[4][1024];
  char* Pb = (char*)&Plds[w][0];

  short8 qa[2][2];
#pragma unroll
  for (int mi = 0; mi < 2; ++mi)
#pragma unroll
    for (int cs = 0; cs < 2; ++cs)
      qa[mi][cs] = *(const short8*)(Qh + (size_t)(qw0 + 16 * mi + c) * 64 + 32 * cs + g * 8);

  f32x4 o[2][4] = {};
  float mrow[2][4], lsum[2][4];
#pragma unroll
  for (int mi = 0; mi < 2; ++mi)
#pragma unroll
    for (int r = 0; r < 4; ++r) { mrow[mi][r] = -1e30f; lsum[mi][r] = 0.f; }

  int kt0 = qw0 - 256; if (kt0 < 0) kt0 = 0;
  const int ktlast = qw0;

  short8 kf[2][2], vf[4];
#pragma unroll
  for (int ni = 0; ni < 2; ++ni)
#pragma unroll
    for (int cs = 0; cs < 2; ++cs)
      kf[ni][cs] = *(const short8*)(Kh + (size_t)(kt0 + 16 * ni + c) * 64 + 32 * cs + g * 8);
#pragma unroll
  for (int ni = 0; ni < 4; ++ni)
    vf[ni] = *(const short8*)(Vt + (size_t)(16 * ni + c) * 2048 + kt0 + g * 8);

  for (int kt = kt0; kt <= ktlast; kt += 32) {
    const int ktn = (kt + 32 <= ktlast) ? kt + 32 : kt;
    short8 kfn[2][2], vfn[4];
#pragma unroll
    for (int ni = 0; ni < 2; ++ni)
#pragma unroll
      for (int cs = 0; cs < 2; ++cs)
        kfn[ni][cs] = *(const short8*)(Kh + (size_t)(ktn + 16 * ni + c) * 64 + 32 * cs + g * 8);
#pragma unroll
    for (int ni = 0; ni < 4; ++ni)
      vfn[ni] = *(const short8*)(Vt + (size_t)(16 * ni + c) * 2048 + ktn + g * 8);

    f32x4 sA[2][2] = {};
#pragma unroll
    for (int mi = 0; mi < 2; ++mi)
#pragma unroll
      for (int ni = 0; ni < 2; ++ni)
#pragma unroll
        for (int cs = 0; cs < 2; ++cs)
          sA[mi][ni] = __builtin_amdgcn_mfma_f32_16x16x32_bf16(qa[mi][cs], kf[ni][cs],
                                                               sA[mi][ni], 0, 0, 0);

    float sv[2][2][4];
#pragma unroll
    for (int mi = 0; mi < 2; ++mi)
#pragma unroll
      for (int ni = 0; ni < 2; ++ni)
#pragma unroll
        for (int r = 0; r < 4; ++r) {
          int q = qw0 + 16 * mi + 4 * g + r;
          int k = kt + 16 * ni + c;
          sv[mi][ni][r] = ((unsigned)(q - k) <= 256u) ? sA[mi][ni][r] * 0.125f : -3.0e38f;
        }

#pragma unroll
    for (int mi = 0; mi < 2; ++mi) {
#pragma unroll
      for (int r = 0; r < 4; ++r) {
        float tm = fmaxf(sv[mi][0][r], sv[mi][1][r]);
        tm = fmaxf(tm, __shfl_xor(tm, 1));
        tm = fmaxf(tm, __shfl_xor(tm, 2));
        tm = fmaxf(tm, __shfl_xor(tm, 4));
        tm = fmaxf(tm, __shfl_xor(tm, 8));
        float mnew = fmaxf(mrow[mi][r], tm);
        float sc = __expf(mrow[mi][r] - mnew);
        mrow[mi][r] = mnew;
        float p0 = __expf(sv[mi][0][r] - mnew);
        float p1 = __expf(sv[mi][1][r] - mnew);
        float ps = p0 + p1;
        ps += __shfl_xor(ps, 1);
        ps += __shfl_xor(ps, 2);
        ps += __shfl_xor(ps, 4);
        ps += __shfl_xor(ps, 8);
        lsum[mi][r] = lsum[mi][r] * sc + ps;
#pragma unroll
        for (int ni = 0; ni < 4; ++ni)
          o[mi][ni][r] *= sc;
        int qloc = 16 * mi + 4 * g + r;
        int xr = (qloc & 12) << 2;
        *(unsigned short*)(Pb + ((qloc * 64 + c * 2) ^ xr)) = f2bf(p0);
        *(unsigned short*)(Pb + ((qloc * 64 + 32 + c * 2) ^ xr)) = f2bf(p1);
      }
    }

#pragma unroll
    for (int mi = 0; mi < 2; ++mi) {
      int qloc = 16 * mi + c;
      short8 pa = *(const short8*)(Pb + ((qloc * 64 + g * 16) ^ ((qloc & 12) << 2)));
#pragma unroll
      for (int ni = 0; ni < 4; ++ni)
        o[mi][ni] = __builtin_amdgcn_mfma_f32_16x16x32_bf16(pa, vf[ni], o[mi][ni], 0, 0, 0);
    }

#pragma unroll
    for (int ni = 0; ni < 2; ++ni)
#pragma unroll
      for (int cs = 0; cs < 2; ++cs)
        kf[ni][cs] = kfn[ni][cs];
#pragma unroll
    for (int ni = 0; ni < 4; ++ni)
      vf[ni] = vfn[ni];
  }

#pragma unroll
  for (int mi = 0; mi < 2; ++mi)
#pragma unroll
    for (int r = 0; r < 4; ++r) {
      float inv = 1.f / lsum[mi][r];
      int q = qw0 + 16 * mi + 4 * g + r;
      unsigned short* row = AO + (size_t)(b * 2048 + q) * 1024 + h * 64 + c;
#pragma unroll
      for (int ni = 0; ni < 4; ++ni)
        row[16 * ni] = f2bf(o[mi][ni][r] * inv);
    }
}

extern "C" void kernel_launch(void* const* d_in, const int* in_sizes, int n_in,
                              void* d_out, int out_size, void* d_ws, size_t ws_size,
                              hipStream_t stream) {
  const float* X  = (const float*)d_in[0];
  const float* wq = (const float*)d_in[1];
  const float* bq = (const float*)d_in[2];
  const float* wk = (const float*)d_in[3];
  const float* bk = (const float*)d_in[4];
  const float* wv = (const float*)d_in[5];
  const float* bv = (const float*)d_in[6];
  const float* wo = (const float*)d_in[7];
  const float* bo = (const float*)d_in[8];
  float* out = (float*)d_out;

  // workspace (ushort elems): Xb[4194304] | Wb[4x1048576] | QKV[3x4194304] | AO[4194304]
  unsigned short* Xb  = (unsigned short*)d_ws;
  unsigned short* Wb  = Xb + 4194304;
  unsigned short* QKV = Wb + 4194304;
  unsigned short* AO  = QKV + 12582912;

  cvt_all<<<dim3(4096, 2), dim3(256), 0, stream>>>(X, wq, wk, wv, wo, Xb, Wb);
  gemm_qkv_fused<<<dim3(8, 32), dim3(512), 0, stream>>>(Xb, Wb, bq, bk, bv, QKV);
  attn_mfma<<<dim3(16, 16, 2), dim3(256), 0, stream>>>(QKV, AO);
  gemm_oproj<<<dim3(8, 32), dim3(512), 0, stream>>>(AO, Wb + 3 * 1048576, bo, out);
}